// Round 1
// baseline (66.234 us; speedup 1.0000x reference)
//
#include <hip/hip_runtime.h>

// out[b,m,n,p] = proj0[b,m] * proj1[b,n] * proj2[m,p]
// proj_j[b,o] = sum_i x[b,i] * w[o,i,j],  x:(96,3) w:(96,3,8)
// NOTE: second matmul's batch broadcast aligns proj2's batch dim with m, not b.

#define NB 96

__global__ __launch_bounds__(256) void nckart_kernel(
    const float* __restrict__ x,   // [96,3]
    const float* __restrict__ w,   // [96,3,8]  w[o,i,j] at o*24 + i*8 + j
    float* __restrict__ out)       // [96,96,96,96] flat
{
    const int bm = blockIdx.x;     // 0..9215
    const int b  = bm / NB;
    const int m  = bm % NB;
    const int t  = threadIdx.x;

    __shared__ float p1[NB];   // proj1[b, n]
    __shared__ float sp[NB];   // proj0[b,m] * proj2[m, p]

    const float xb0 = x[b*3 + 0], xb1 = x[b*3 + 1], xb2 = x[b*3 + 2];

    if (t < NB) {
        // proj1[b, t]
        p1[t] = xb0 * w[t*24 + 0*8 + 1]
              + xb1 * w[t*24 + 1*8 + 1]
              + xb2 * w[t*24 + 2*8 + 1];
    } else if (t < 2*NB) {
        const int p = t - NB;
        const float xm0 = x[m*3 + 0], xm1 = x[m*3 + 1], xm2 = x[m*3 + 2];
        // s = proj0[b, m]
        const float s = xb0 * w[m*24 + 0*8 + 0]
                      + xb1 * w[m*24 + 1*8 + 0]
                      + xb2 * w[m*24 + 2*8 + 0];
        // proj2[m, p]
        const float p2 = xm0 * w[p*24 + 0*8 + 2]
                       + xm1 * w[p*24 + 1*8 + 2]
                       + xm2 * w[p*24 + 2*8 + 2];
        sp[p] = s * p2;
    }
    __syncthreads();

    // Tile for this (b,m): 96*96 floats = 2304 float4, 256 threads x 9 iters.
    float4* out4 = reinterpret_cast<float4*>(out + (size_t)bm * (NB * NB));
    const float4* sp4 = reinterpret_cast<const float4*>(sp);

    #pragma unroll
    for (int it = 0; it < 9; ++it) {
        const int idx = t + it * 256;   // 0..2303
        const int n   = idx / 24;       // row (n index)
        const int p4  = idx % 24;       // float4 index within row
        float4 v = sp4[p4];
        const float a = p1[n];
        v.x *= a; v.y *= a; v.z *= a; v.w *= a;
        out4[idx] = v;
    }
}

extern "C" void kernel_launch(void* const* d_in, const int* in_sizes, int n_in,
                              void* d_out, int out_size, void* d_ws, size_t ws_size,
                              hipStream_t stream) {
    const float* x = (const float*)d_in[0];
    const float* w = (const float*)d_in[1];
    float* out = (float*)d_out;

    const int grid = NB * NB;   // one block per (b, m)
    nckart_kernel<<<grid, 256, 0, stream>>>(x, w, out);
}